// Round 1
// baseline (785.168 us; speedup 1.0000x reference)
//
#include <hip/hip_runtime.h>
#include <hip/hip_bf16.h>

typedef __attribute__((ext_vector_type(8))) short s8v;
typedef __attribute__((ext_vector_type(4))) short s4v;
typedef __attribute__((ext_vector_type(4))) float f4v;

#define MFMA32(A,B,C) __builtin_amdgcn_mfma_f32_16x16x32_bf16(A,B,C,0,0,0)
#define MFMA16(A,B,C) __builtin_amdgcn_mfma_f32_16x16x16bf16_1k(A,B,C,0,0,0)

__device__ __forceinline__ unsigned short f2bf(float f){
  unsigned int u = __float_as_uint(f);
  u += 0x7FFFu + ((u>>16)&1u);
  return (unsigned short)(u>>16);
}
__device__ __forceinline__ float bf2f(unsigned short s){
  return __uint_as_float(((unsigned int)s)<<16);
}

// log2(e)/8  (fold the 1/sqrt(dh)=1/8 score scale into exp2)
#define EXPC 0.18033688011112042f

// ---------------------------------------------------------------------------
// K0: Wo' [o][h*64+j] = Wo[o][j*16+h], bf16
// ---------------------------------------------------------------------------
__global__ void pack_wo(const float* __restrict__ wo, unsigned short* __restrict__ wop){
  int idx = blockIdx.x*256 + threadIdx.x;
  if(idx >= 1024*1024) return;
  int o = idx >> 10, r = idx & 1023, h = r >> 6, j = r & 63;
  wop[idx] = f2bf(wo[o*1024 + j*16 + h]);
}

// ---------------------------------------------------------------------------
// K1: projections. C[m,n] = sum_k A[m,k] * W[n,k] + bias[n]
//   z=0: KEY  -> kh[b][h][s][j]     (j = n>>4, h = n&15)
//   z=1: QUERY-> qh[b][h][s][j]
//   z=2: VALUE-> vt[b][h][j][s]     (transposed for PV A-fragments)
// 128x128 block tile, BK=64, 4 waves each 64x64 (4x4 of 16x16x32 MFMA)
// ---------------------------------------------------------------------------
__global__ __launch_bounds__(256) void proj_gemm(
    const float* __restrict__ KEY, const float* __restrict__ VALUE, const float* __restrict__ QUERY,
    const float* __restrict__ Wk, const float* __restrict__ bk,
    const float* __restrict__ Wq, const float* __restrict__ bq,
    const float* __restrict__ Wv, const float* __restrict__ bv,
    unsigned short* __restrict__ kh, unsigned short* __restrict__ qh,
    unsigned short* __restrict__ vt)
{
  __shared__ short As[128*64];
  __shared__ short Bs[128*64];
  const int t = threadIdx.x;
  const int z = blockIdx.z;
  const float* A; const float* W; const float* bias;
  if(z==0){A=KEY;   W=Wk; bias=bk;}
  else if(z==1){A=QUERY; W=Wq; bias=bq;}
  else {A=VALUE; W=Wv; bias=bv;}
  const int m0 = blockIdx.x*128, n0 = blockIdx.y*128;
  const int l = t&63, w = t>>6;
  const int wm = (w>>1)*64, wn = (w&1)*64;
  const int row16 = l&15, quad = l>>4;
  f4v acc[4][4];
  #pragma unroll
  for(int i=0;i<4;i++)
    #pragma unroll
    for(int j=0;j<4;j++) acc[i][j] = (f4v){0.f,0.f,0.f,0.f};

  const int sr = t>>4, sc = t&15;   // staging: 16 rows x 16 float4-chunks per pass
  for(int k0=0;k0<1024;k0+=64){
    #pragma unroll
    for(int p=0;p<8;p++){
      float4 av = *(const float4*)&A[(size_t)(m0 + p*16 + sr)*1024 + k0 + sc*4];
      float4 bvv= *(const float4*)&W[(size_t)(n0 + p*16 + sr)*1024 + k0 + sc*4];
      s4v ap, bp;
      ap[0]=(short)f2bf(av.x); ap[1]=(short)f2bf(av.y); ap[2]=(short)f2bf(av.z); ap[3]=(short)f2bf(av.w);
      bp[0]=(short)f2bf(bvv.x);bp[1]=(short)f2bf(bvv.y);bp[2]=(short)f2bf(bvv.z);bp[3]=(short)f2bf(bvv.w);
      *(s4v*)&As[(p*16+sr)*64 + sc*4] = ap;
      *(s4v*)&Bs[(p*16+sr)*64 + sc*4] = bp;
    }
    __syncthreads();
    #pragma unroll
    for(int kk=0; kk<64; kk+=32){
      s8v af[4], bf[4];
      #pragma unroll
      for(int mt=0;mt<4;mt++) af[mt] = *(const s8v*)&As[(wm+mt*16+row16)*64 + kk + quad*8];
      #pragma unroll
      for(int nt=0;nt<4;nt++) bf[nt] = *(const s8v*)&Bs[(wn+nt*16+row16)*64 + kk + quad*8];
      #pragma unroll
      for(int mt=0;mt<4;mt++)
        #pragma unroll
        for(int nt=0;nt<4;nt++)
          acc[mt][nt] = MFMA32(af[mt], bf[nt], acc[mt][nt]);
    }
    __syncthreads();
  }

  #pragma unroll
  for(int nt=0;nt<4;nt++){
    const int n = n0 + wn + nt*16 + row16;
    const float bias_n = bias[n];
    const int hh = n & 15, jj = n >> 4;
    #pragma unroll
    for(int mt=0;mt<4;mt++){
      #pragma unroll
      for(int r=0;r<4;r++){
        const int m = m0 + wm + mt*16 + quad*4 + r;
        const float val = acc[mt][nt][r] + bias_n;
        const int bb = m>>11, ss = m&2047;
        if(z==2)
          vt[(size_t)((bb*16+hh)*64 + jj)*2048 + ss] = f2bf(val);
        else if(z==0)
          kh[(size_t)((bb*16+hh)*2048 + ss)*64 + jj] = f2bf(val);
        else
          qh[(size_t)((bb*16+hh)*2048 + ss)*64 + jj] = f2bf(val);
      }
    }
  }
}

// ---------------------------------------------------------------------------
// K2: rden[b][i][q] = 1 / sum_h exp(s_h(i,q)/8)   (softmax over heads!)
// wave: 16-row key slice; lane-local reduction over the 16 head accumulators
// grid: (32 i-blocks of 64, 4 q-chunks of 512, 2 batches), 256 thr
// ---------------------------------------------------------------------------
__global__ __launch_bounds__(256,2) void attn_denom(
    const unsigned short* __restrict__ kh, const unsigned short* __restrict__ qh,
    unsigned short* __restrict__ rden)
{
  const int t=threadIdx.x, l=t&63, w=t>>6;
  const int row16=l&15, quad=l>>4;
  const int bz = blockIdx.z;
  const int i0 = blockIdx.x*64 + w*16;
  const int qbase = blockIdx.y*512;
  s8v kf[16][2];
  #pragma unroll
  for(int h=0;h<16;h++){
    const unsigned short* kp = &kh[(size_t)((bz*16+h)*2048 + i0 + row16)*64];
    kf[h][0] = *(const s8v*)&kp[quad*8];
    kf[h][1] = *(const s8v*)&kp[32+quad*8];
  }
  for(int qs=0; qs<32; qs++){
    const int q0 = qbase + qs*16;
    float dsum0=0.f, dsum1=0.f, dsum2=0.f, dsum3=0.f;
    #pragma unroll
    for(int h=0;h<16;h++){
      const unsigned short* qp = &qh[(size_t)((bz*16+h)*2048 + q0 + row16)*64];
      s8v qf0 = *(const s8v*)&qp[quad*8];
      s8v qf1 = *(const s8v*)&qp[32+quad*8];
      f4v Sv = (f4v){0.f,0.f,0.f,0.f};
      Sv = MFMA32(kf[h][0], qf0, Sv);
      Sv = MFMA32(kf[h][1], qf1, Sv);
      dsum0 += __builtin_amdgcn_exp2f(Sv[0]*EXPC);
      dsum1 += __builtin_amdgcn_exp2f(Sv[1]*EXPC);
      dsum2 += __builtin_amdgcn_exp2f(Sv[2]*EXPC);
      dsum3 += __builtin_amdgcn_exp2f(Sv[3]*EXPC);
    }
    const int qcol = q0 + row16;
    rden[(size_t)(bz*2048 + i0 + quad*4 + 0)*2048 + qcol] = f2bf(1.0f/dsum0);
    rden[(size_t)(bz*2048 + i0 + quad*4 + 1)*2048 + qcol] = f2bf(1.0f/dsum1);
    rden[(size_t)(bz*2048 + i0 + quad*4 + 2)*2048 + qcol] = f2bf(1.0f/dsum2);
    rden[(size_t)(bz*2048 + i0 + quad*4 + 3)*2048 + qcol] = f2bf(1.0f/dsum3);
  }
}

// ---------------------------------------------------------------------------
// K3: out2[b][q][h*64+j] = sum_i (exp(s/8)*rden) * v[b,h,i,j]
// Per block: one (b, h, q-block of 64). Wave = 16-q subtile, full key loop.
// attn C-tile feeds PV 16x16x16 MFMA as B-fragment directly (layout match).
// ---------------------------------------------------------------------------
__global__ __launch_bounds__(256) void attn_pv(
    const unsigned short* __restrict__ kh, const unsigned short* __restrict__ qh,
    const unsigned short* __restrict__ vt, const unsigned short* __restrict__ rden,
    unsigned short* __restrict__ out2)
{
  __shared__ unsigned short stage[4*16*72];
  const int t=threadIdx.x, l=t&63, w=t>>6;
  const int row16=l&15, quad=l>>4;
  const int qb = blockIdx.x;   // 0..31
  const int h  = blockIdx.y;   // 0..15
  const int bz = blockIdx.z;   // 0..1
  const int q0 = qb*64 + w*16;

  const unsigned short* qp = &qh[(size_t)((bz*16+h)*2048 + q0 + row16)*64];
  const s8v qf0 = *(const s8v*)&qp[quad*8];
  const s8v qf1 = *(const s8v*)&qp[32+quad*8];
  f4v o0=(f4v){0,0,0,0}, o1=(f4v){0,0,0,0}, o2=(f4v){0,0,0,0}, o3=(f4v){0,0,0,0};

  const unsigned short* kbase = &kh[(size_t)((bz*16+h)*2048)*64];
  const unsigned short* vbase = &vt[(size_t)((bz*16+h)*64)*2048];
  const unsigned short* dbase = &rden[(size_t)(bz*2048)*2048];

  for(int i0=0;i0<2048;i0+=32){
    f4v S0=(f4v){0,0,0,0}, S1=(f4v){0,0,0,0};
    {
      const unsigned short* kp0 = &kbase[(size_t)(i0 + row16)*64];
      const unsigned short* kp1 = &kbase[(size_t)(i0 + 16 + row16)*64];
      S0 = MFMA32(*(const s8v*)&kp0[quad*8],    qf0, S0);
      S0 = MFMA32(*(const s8v*)&kp0[32+quad*8], qf1, S0);
      S1 = MFMA32(*(const s8v*)&kp1[quad*8],    qf0, S1);
      S1 = MFMA32(*(const s8v*)&kp1[32+quad*8], qf1, S1);
    }
    s4v p0, p1;
    #pragma unroll
    for(int r=0;r<4;r++){
      const int i_a = i0 + quad*4 + r;
      float ra = bf2f(dbase[(size_t)i_a*2048      + q0 + row16]);
      float rb = bf2f(dbase[(size_t)(i_a+16)*2048 + q0 + row16]);
      p0[r] = (short)f2bf(__builtin_amdgcn_exp2f(S0[r]*EXPC) * ra);
      p1[r] = (short)f2bf(__builtin_amdgcn_exp2f(S1[r]*EXPC) * rb);
    }
    #pragma unroll
    for(int jt=0;jt<4;jt++){
      const unsigned short* vp = &vbase[(size_t)(jt*16 + row16)*2048 + i0];
      s4v v0 = *(const s4v*)&vp[quad*4];
      s4v v1 = *(const s4v*)&vp[16+quad*4];
      f4v* op = (jt==0)?&o0:(jt==1)?&o1:(jt==2)?&o2:&o3;
      *op = MFMA16(v0, p0, *op);
      *op = MFMA16(v1, p1, *op);
    }
  }
  // stage [64 q][64 j] through LDS for coalesced h-major writes
  #pragma unroll
  for(int jt=0;jt<4;jt++){
    const f4v* op = (jt==0)?&o0:(jt==1)?&o1:(jt==2)?&o2:&o3;
    s4v pk;
    #pragma unroll
    for(int r=0;r<4;r++) pk[r] = (short)f2bf((*op)[r]);
    *(s4v*)&stage[(w*16 + row16)*72 + jt*16 + quad*4] = pk;
  }
  __syncthreads();
  const int qblk = t>>2, jc = (t&3)*16;
  const unsigned short* src = &stage[qblk*72 + jc];
  unsigned short* dst = &out2[(size_t)(bz*2048 + qb*64 + qblk)*1024 + h*64 + jc];
  #pragma unroll
  for(int u=0;u<4;u++) *(s4v*)&dst[u*4] = *(const s4v*)&src[u*4];
}

// ---------------------------------------------------------------------------
// K4: res[m][n] = sum_k out2[m,k]*WoP[n,k] + bo[n], fp32 out
// ---------------------------------------------------------------------------
__global__ __launch_bounds__(256) void out_gemm(
    const unsigned short* __restrict__ A, const unsigned short* __restrict__ Bm,
    const float* __restrict__ bias, float* __restrict__ out)
{
  __shared__ short As[128*64];
  __shared__ short Bs[128*64];
  const int t=threadIdx.x, l=t&63, w=t>>6;
  const int row16=l&15, quad=l>>4;
  const int m0=blockIdx.x*128, n0=blockIdx.y*128;
  const int wm=(w>>1)*64, wn=(w&1)*64;
  f4v acc[4][4];
  #pragma unroll
  for(int i=0;i<4;i++)
    #pragma unroll
    for(int j=0;j<4;j++) acc[i][j] = (f4v){0.f,0.f,0.f,0.f};

  const int sr=t>>3, sc=(t&7)*8;
  for(int k0=0;k0<1024;k0+=64){
    #pragma unroll
    for(int p=0;p<4;p++){
      *(s8v*)&As[(p*32+sr)*64 + sc] = *(const s8v*)&A [(size_t)(m0+p*32+sr)*1024 + k0 + sc];
      *(s8v*)&Bs[(p*32+sr)*64 + sc] = *(const s8v*)&Bm[(size_t)(n0+p*32+sr)*1024 + k0 + sc];
    }
    __syncthreads();
    #pragma unroll
    for(int kk=0; kk<64; kk+=32){
      s8v af[4], bf[4];
      #pragma unroll
      for(int mt=0;mt<4;mt++) af[mt] = *(const s8v*)&As[(wm+mt*16+row16)*64 + kk + quad*8];
      #pragma unroll
      for(int nt=0;nt<4;nt++) bf[nt] = *(const s8v*)&Bs[(wn+nt*16+row16)*64 + kk + quad*8];
      #pragma unroll
      for(int mt=0;mt<4;mt++)
        #pragma unroll
        for(int nt=0;nt<4;nt++)
          acc[mt][nt] = MFMA32(af[mt], bf[nt], acc[mt][nt]);
    }
    __syncthreads();
  }
  #pragma unroll
  for(int nt=0;nt<4;nt++){
    const int n = n0+wn+nt*16+row16;
    const float bias_n = bias[n];
    #pragma unroll
    for(int mt=0;mt<4;mt++)
      #pragma unroll
      for(int r=0;r<4;r++){
        const int m = m0+wm+mt*16+quad*4+r;
        out[(size_t)m*1024 + n] = acc[mt][nt][r] + bias_n;
      }
  }
}

// ---------------------------------------------------------------------------
extern "C" void kernel_launch(void* const* d_in, const int* in_sizes, int n_in,
                              void* d_out, int out_size, void* d_ws, size_t ws_size,
                              hipStream_t stream)
{
  const float* KEY   = (const float*)d_in[0];
  const float* VALUE = (const float*)d_in[1];
  const float* QUERY = (const float*)d_in[2];
  const float* Wk = (const float*)d_in[3];
  const float* bk = (const float*)d_in[4];
  const float* Wq = (const float*)d_in[5];
  const float* bq = (const float*)d_in[6];
  const float* Wv = (const float*)d_in[7];
  const float* bv = (const float*)d_in[8];
  const float* Wo = (const float*)d_in[9];
  const float* bo = (const float*)d_in[10];

  char* ws = (char*)d_ws;
  unsigned short* kh   = (unsigned short*)(ws);                        //  8 MiB: [2][16][2048][64]
  unsigned short* qh   = (unsigned short*)(ws +   8388608);            //  8 MiB
  unsigned short* vt   = (unsigned short*)(ws + 2*8388608);            //  8 MiB: [2][16][64][2048]
  unsigned short* out2 = (unsigned short*)(ws + 3*8388608);            //  8 MiB: [2][2048][1024]
  unsigned short* wop  = (unsigned short*)(ws + 4*8388608);            //  2 MiB
  unsigned short* rden = (unsigned short*)(ws + 4*8388608 + 2097152);  // 16 MiB: [2][2048][2048]

  pack_wo  <<<dim3(4096),    dim3(256), 0, stream>>>(Wo, wop);
  proj_gemm<<<dim3(32,8,3),  dim3(256), 0, stream>>>(KEY,VALUE,QUERY,Wk,bk,Wq,bq,Wv,bv,kh,qh,vt);
  attn_denom<<<dim3(32,4,2), dim3(256), 0, stream>>>(kh,qh,rden);
  attn_pv  <<<dim3(32,16,2), dim3(256), 0, stream>>>(kh,qh,vt,rden,out2);
  out_gemm <<<dim3(32,8),    dim3(256), 0, stream>>>(out2,wop,bo,(float*)d_out);
}

// Round 2
// 612.254 us; speedup vs baseline: 1.2824x; 1.2824x over previous
//
#include <hip/hip_runtime.h>
#include <hip/hip_bf16.h>

typedef __attribute__((ext_vector_type(8))) short s8v;
typedef __attribute__((ext_vector_type(4))) short s4v;
typedef __attribute__((ext_vector_type(4))) float f4v;

#define MFMA32(A,B,C) __builtin_amdgcn_mfma_f32_16x16x32_bf16(A,B,C,0,0,0)
#define MFMA16(A,B,C) __builtin_amdgcn_mfma_f32_16x16x16bf16_1k(A,B,C,0,0,0)

__device__ __forceinline__ unsigned short f2bf(float f){
  unsigned int u = __float_as_uint(f);
  u += 0x7FFFu + ((u>>16)&1u);
  return (unsigned short)(u>>16);
}
__device__ __forceinline__ float bf2f(unsigned short s){
  return __uint_as_float(((unsigned int)s)<<16);
}

// log2(e)/8  (fold the 1/sqrt(dh)=1/8 score scale into exp2)
#define EXPC 0.18033688011112042f

// ---------------------------------------------------------------------------
// K0: Wo' [o][h*64+j] = Wo[o][j*16+h], bf16
// ---------------------------------------------------------------------------
__global__ void pack_wo(const float* __restrict__ wo, unsigned short* __restrict__ wop){
  int idx = blockIdx.x*256 + threadIdx.x;
  if(idx >= 1024*1024) return;
  int o = idx >> 10, r = idx & 1023, h = r >> 6, j = r & 63;
  wop[idx] = f2bf(wo[o*1024 + j*16 + h]);
}

// ---------------------------------------------------------------------------
// K1: projections. C[m,n] = sum_k A[m,k] * W[n,k] + bias[n]
//   z=0: KEY  -> kh[b][h][s][j]     (j = n>>4, h = n&15)
//   z=1: QUERY-> qh[b][h][s][j]
//   z=2: VALUE-> vt[b][h][j][s]     (transposed for PV A-fragments)
// ---------------------------------------------------------------------------
__global__ __launch_bounds__(256) void proj_gemm(
    const float* __restrict__ KEY, const float* __restrict__ VALUE, const float* __restrict__ QUERY,
    const float* __restrict__ Wk, const float* __restrict__ bk,
    const float* __restrict__ Wq, const float* __restrict__ bq,
    const float* __restrict__ Wv, const float* __restrict__ bv,
    unsigned short* __restrict__ kh, unsigned short* __restrict__ qh,
    unsigned short* __restrict__ vt)
{
  __shared__ short As[128*64];
  __shared__ short Bs[128*64];
  const int t = threadIdx.x;
  const int z = blockIdx.z;
  const float* A; const float* W; const float* bias;
  if(z==0){A=KEY;   W=Wk; bias=bk;}
  else if(z==1){A=QUERY; W=Wq; bias=bq;}
  else {A=VALUE; W=Wv; bias=bv;}
  const int m0 = blockIdx.x*128, n0 = blockIdx.y*128;
  const int l = t&63, w = t>>6;
  const int wm = (w>>1)*64, wn = (w&1)*64;
  const int row16 = l&15, quad = l>>4;
  f4v acc[4][4];
  #pragma unroll
  for(int i=0;i<4;i++)
    #pragma unroll
    for(int j=0;j<4;j++) acc[i][j] = (f4v){0.f,0.f,0.f,0.f};

  const int sr = t>>4, sc = t&15;
  for(int k0=0;k0<1024;k0+=64){
    #pragma unroll
    for(int p=0;p<8;p++){
      float4 av = *(const float4*)&A[(size_t)(m0 + p*16 + sr)*1024 + k0 + sc*4];
      float4 bvv= *(const float4*)&W[(size_t)(n0 + p*16 + sr)*1024 + k0 + sc*4];
      s4v ap, bp;
      ap[0]=(short)f2bf(av.x); ap[1]=(short)f2bf(av.y); ap[2]=(short)f2bf(av.z); ap[3]=(short)f2bf(av.w);
      bp[0]=(short)f2bf(bvv.x);bp[1]=(short)f2bf(bvv.y);bp[2]=(short)f2bf(bvv.z);bp[3]=(short)f2bf(bvv.w);
      *(s4v*)&As[(p*16+sr)*64 + sc*4] = ap;
      *(s4v*)&Bs[(p*16+sr)*64 + sc*4] = bp;
    }
    __syncthreads();
    #pragma unroll
    for(int kk=0; kk<64; kk+=32){
      s8v af[4], bf[4];
      #pragma unroll
      for(int mt=0;mt<4;mt++) af[mt] = *(const s8v*)&As[(wm+mt*16+row16)*64 + kk + quad*8];
      #pragma unroll
      for(int nt=0;nt<4;nt++) bf[nt] = *(const s8v*)&Bs[(wn+nt*16+row16)*64 + kk + quad*8];
      #pragma unroll
      for(int mt=0;mt<4;mt++)
        #pragma unroll
        for(int nt=0;nt<4;nt++)
          acc[mt][nt] = MFMA32(af[mt], bf[nt], acc[mt][nt]);
    }
    __syncthreads();
  }

  #pragma unroll
  for(int nt=0;nt<4;nt++){
    const int n = n0 + wn + nt*16 + row16;
    const float bias_n = bias[n];
    const int hh = n & 15, jj = n >> 4;
    #pragma unroll
    for(int mt=0;mt<4;mt++){
      #pragma unroll
      for(int r=0;r<4;r++){
        const int m = m0 + wm + mt*16 + quad*4 + r;
        const float val = acc[mt][nt][r] + bias_n;
        const int bb = m>>11, ss = m&2047;
        if(z==2)
          vt[(size_t)((bb*16+hh)*64 + jj)*2048 + ss] = f2bf(val);
        else if(z==0)
          kh[(size_t)((bb*16+hh)*2048 + ss)*64 + jj] = f2bf(val);
        else
          qh[(size_t)((bb*16+hh)*2048 + ss)*64 + jj] = f2bf(val);
      }
    }
  }
}

// ---------------------------------------------------------------------------
// K2: fused attention. Softmax couples only the 16 heads at fixed (i,q), so
// one block holds all 16 heads (4 waves x 4 heads) per q16-group; only the
// 4-head partial denominators cross waves (LDS, parity double-buffered,
// ONE barrier per i32-tile). QK computed exactly once; P stays in registers
// (MFMA C-layout == MFMA16 B-fragment layout). Block: 8 waves = 2 q-groups.
// Grid: (qb=64 [q32], ih=2 [i1024], b=2) = 256 blocks = 1/CU.
// Output: bf16 partial O per ih half -> reduce_o.
// ---------------------------------------------------------------------------
__global__ __launch_bounds__(512,1) void fused_attn(
    const unsigned short* __restrict__ kh, const unsigned short* __restrict__ qh,
    const unsigned short* __restrict__ vt, unsigned short* __restrict__ opart)
{
  __shared__ f4v dpart[2][2][4][2][64];   // [parity][qg][hg][sub][lane] = 32 KB
  const int t=threadIdx.x, l=t&63, w=t>>6;
  const int qg=w>>2, hg=w&3;
  const int row16=l&15, quad=l>>4;
  const int qb=blockIdx.x, ih=blockIdx.y, b=blockIdx.z;
  const int q0 = qb*32 + qg*16;
  const int h0 = hg*4;
  const int ibase = ih*1024;

  s8v qf[4][2];
  const unsigned short* kb[4];
  const unsigned short* vb[4];
  #pragma unroll
  for(int hh=0;hh<4;hh++){
    const int h = h0+hh;
    const unsigned short* qp = &qh[(size_t)((b*16+h)*2048 + q0 + row16)*64];
    qf[hh][0] = *(const s8v*)&qp[quad*8];
    qf[hh][1] = *(const s8v*)&qp[32+quad*8];
    kb[hh] = &kh[(size_t)((b*16+h)*2048 + ibase + row16)*64];
    vb[hh] = &vt[(size_t)((b*16+h)*64 + row16)*2048 + ibase];
  }
  f4v o[4][4];
  #pragma unroll
  for(int i=0;i<4;i++)
    #pragma unroll
    for(int j=0;j<4;j++) o[i][j] = (f4v){0.f,0.f,0.f,0.f};

  for(int i0=0;i0<1024;i0+=32){
    f4v e0[4], e1[4];
    #pragma unroll
    for(int hh=0;hh<4;hh++){
      const unsigned short* kp = kb[hh] + (size_t)i0*64;
      f4v S0 = (f4v){0.f,0.f,0.f,0.f};
      f4v S1 = (f4v){0.f,0.f,0.f,0.f};
      S0 = MFMA32(*(const s8v*)&kp[quad*8],         qf[hh][0], S0);
      S0 = MFMA32(*(const s8v*)&kp[32+quad*8],      qf[hh][1], S0);
      S1 = MFMA32(*(const s8v*)&kp[1024+quad*8],    qf[hh][0], S1);
      S1 = MFMA32(*(const s8v*)&kp[1024+32+quad*8], qf[hh][1], S1);
      #pragma unroll
      for(int r=0;r<4;r++){
        e0[hh][r] = __builtin_amdgcn_exp2f(S0[r]*EXPC);
        e1[hh][r] = __builtin_amdgcn_exp2f(S1[r]*EXPC);
      }
    }
    f4v d0 = (e0[0]+e0[1])+(e0[2]+e0[3]);
    f4v d1 = (e1[0]+e1[1])+(e1[2]+e1[3]);
    const int par = (i0>>5)&1;
    dpart[par][qg][hg][0][l] = d0;
    dpart[par][qg][hg][1][l] = d1;
    __syncthreads();
    f4v s0 = (dpart[par][qg][0][0][l]+dpart[par][qg][1][0][l])
           + (dpart[par][qg][2][0][l]+dpart[par][qg][3][0][l]);
    f4v s1 = (dpart[par][qg][0][1][l]+dpart[par][qg][1][1][l])
           + (dpart[par][qg][2][1][l]+dpart[par][qg][3][1][l]);
    f4v r0, r1;
    #pragma unroll
    for(int r=0;r<4;r++){
      r0[r] = __builtin_amdgcn_rcpf(s0[r]);
      r1[r] = __builtin_amdgcn_rcpf(s1[r]);
    }
    s4v p0[4], p1[4];
    #pragma unroll
    for(int hh=0;hh<4;hh++){
      #pragma unroll
      for(int r=0;r<4;r++){
        p0[hh][r] = (short)f2bf(e0[hh][r]*r0[r]);
        p1[hh][r] = (short)f2bf(e1[hh][r]*r1[r]);
      }
    }
    #pragma unroll
    for(int hh=0;hh<4;hh++){
      #pragma unroll
      for(int jt=0;jt<4;jt++){
        const unsigned short* vp = vb[hh] + (size_t)jt*16*2048 + i0;
        s4v v0 = *(const s4v*)&vp[quad*4];
        s4v v1 = *(const s4v*)&vp[16+quad*4];
        o[hh][jt] = MFMA16(v0, p0[hh], o[hh][jt]);
        o[hh][jt] = MFMA16(v1, p1[hh], o[hh][jt]);
      }
    }
  }
  // store bf16 partial: opart[ih][b][q][h*64+j]
  #pragma unroll
  for(int hh=0;hh<4;hh++){
    #pragma unroll
    for(int jt=0;jt<4;jt++){
      s4v ov;
      #pragma unroll
      for(int r=0;r<4;r++) ov[r] = (short)f2bf(o[hh][jt][r]);
      *(s4v*)&opart[(size_t)((ih*2+b)*2048 + q0+row16)*1024 + (h0+hh)*64 + jt*16 + quad*4] = ov;
    }
  }
}

// ---------------------------------------------------------------------------
// K3: reduce the 2 i-half partials -> out2 bf16
// ---------------------------------------------------------------------------
__global__ __launch_bounds__(256) void reduce_o(
    const unsigned short* __restrict__ op, unsigned short* __restrict__ out2)
{
  size_t e = ((size_t)blockIdx.x*256 + threadIdx.x)*8;
  s8v a = *(const s8v*)&op[e];
  s8v b = *(const s8v*)&op[4194304 + e];
  s8v r;
  #pragma unroll
  for(int i=0;i<8;i++)
    r[i] = (short)f2bf(bf2f((unsigned short)a[i]) + bf2f((unsigned short)b[i]));
  *(s8v*)&out2[e] = r;
}

// ---------------------------------------------------------------------------
// K4: res[m][n] = sum_k out2[m,k]*WoP[n,k] + bo[n], fp32 out
// ---------------------------------------------------------------------------
__global__ __launch_bounds__(256) void out_gemm(
    const unsigned short* __restrict__ A, const unsigned short* __restrict__ Bm,
    const float* __restrict__ bias, float* __restrict__ out)
{
  __shared__ short As[128*64];
  __shared__ short Bs[128*64];
  const int t=threadIdx.x, l=t&63, w=t>>6;
  const int row16=l&15, quad=l>>4;
  const int m0=blockIdx.x*128, n0=blockIdx.y*128;
  const int wm=(w>>1)*64, wn=(w&1)*64;
  f4v acc[4][4];
  #pragma unroll
  for(int i=0;i<4;i++)
    #pragma unroll
    for(int j=0;j<4;j++) acc[i][j] = (f4v){0.f,0.f,0.f,0.f};

  const int sr=t>>3, sc=(t&7)*8;
  for(int k0=0;k0<1024;k0+=64){
    #pragma unroll
    for(int p=0;p<4;p++){
      *(s8v*)&As[(p*32+sr)*64 + sc] = *(const s8v*)&A [(size_t)(m0+p*32+sr)*1024 + k0 + sc];
      *(s8v*)&Bs[(p*32+sr)*64 + sc] = *(const s8v*)&Bm[(size_t)(n0+p*32+sr)*1024 + k0 + sc];
    }
    __syncthreads();
    #pragma unroll
    for(int kk=0; kk<64; kk+=32){
      s8v af[4], bf[4];
      #pragma unroll
      for(int mt=0;mt<4;mt++) af[mt] = *(const s8v*)&As[(wm+mt*16+row16)*64 + kk + quad*8];
      #pragma unroll
      for(int nt=0;nt<4;nt++) bf[nt] = *(const s8v*)&Bs[(wn+nt*16+row16)*64 + kk + quad*8];
      #pragma unroll
      for(int mt=0;mt<4;mt++)
        #pragma unroll
        for(int nt=0;nt<4;nt++)
          acc[mt][nt] = MFMA32(af[mt], bf[nt], acc[mt][nt]);
    }
    __syncthreads();
  }
  #pragma unroll
  for(int nt=0;nt<4;nt++){
    const int n = n0+wn+nt*16+row16;
    const float bias_n = bias[n];
    #pragma unroll
    for(int mt=0;mt<4;mt++)
      #pragma unroll
      for(int r=0;r<4;r++){
        const int m = m0+wm+mt*16+quad*4+r;
        out[(size_t)m*1024 + n] = acc[mt][nt][r] + bias_n;
      }
  }
}

// ---------------------------------------------------------------------------
extern "C" void kernel_launch(void* const* d_in, const int* in_sizes, int n_in,
                              void* d_out, int out_size, void* d_ws, size_t ws_size,
                              hipStream_t stream)
{
  const float* KEY   = (const float*)d_in[0];
  const float* VALUE = (const float*)d_in[1];
  const float* QUERY = (const float*)d_in[2];
  const float* Wk = (const float*)d_in[3];
  const float* bk = (const float*)d_in[4];
  const float* Wq = (const float*)d_in[5];
  const float* bq = (const float*)d_in[6];
  const float* Wv = (const float*)d_in[7];
  const float* bv = (const float*)d_in[8];
  const float* Wo = (const float*)d_in[9];
  const float* bo = (const float*)d_in[10];

  char* ws = (char*)d_ws;
  unsigned short* kh   = (unsigned short*)(ws);                 //  8 MiB [2][16][2048][64]
  unsigned short* qh   = (unsigned short*)(ws +  8388608);      //  8 MiB
  unsigned short* vt   = (unsigned short*)(ws + 16777216);      //  8 MiB [2][16][64][2048]
  unsigned short* out2 = (unsigned short*)(ws + 25165824);      //  8 MiB [2][2048][1024]
  unsigned short* wop  = (unsigned short*)(ws + 33554432);      //  2 MiB
  unsigned short* opart= (unsigned short*)(ws + 35651584);      // 16 MiB [2ih][2][2048][1024]

  pack_wo   <<<dim3(4096),   dim3(256), 0, stream>>>(Wo, wop);
  proj_gemm <<<dim3(32,8,3), dim3(256), 0, stream>>>(KEY,VALUE,QUERY,Wk,bk,Wq,bq,Wv,bv,kh,qh,vt);
  fused_attn<<<dim3(64,2,2), dim3(512), 0, stream>>>(kh,qh,vt,opart);
  reduce_o  <<<dim3(2048),   dim3(256), 0, stream>>>(opart,out2);
  out_gemm  <<<dim3(32,8),   dim3(256), 0, stream>>>(out2,wop,bo,(float*)d_out);
}